// Round 20
// baseline (244.229 us; speedup 1.0000x reference)
//
#include <hip/hip_runtime.h>
#include <stdint.h>
#include <math.h>

typedef uint16_t u16; typedef uint32_t u32;
typedef __bf16 bf16x8 __attribute__((ext_vector_type(8)));
typedef float  f32x4  __attribute__((ext_vector_type(4)));
typedef u32 __attribute__((address_space(1))) gu32;
typedef u32 __attribute__((address_space(3))) lu32;

// ---- ws layout ----
#define FOFF_FUP    0        // 12 floats (up==down filter)
#define FOFF_KG     16       // 4
#define FOFF_GAUSS  24       // 9
#define FOFF_PART   40       // 8 per-batch styles^2 partial sums
#define FOFF_H3     48       // 36*64
#define FOFF_STYLES 2368     // 8*512
#define FOFF_KK     6464     // 9*512  (tap-major)
#define OFFB_WB  ((size_t)65536)          // 8*512*512 bf16 = 4MB (ends 4259840)
#define OFFB_MUV ((size_t)4456448)        // Uv[48][32]  = 3072 B
#define OFFB_MUH ((size_t)4459520)        // Uh[144][96] = 27648 B
#define OFFB_MDV ((size_t)4487168)        // Dv[16][64]  = 2048 B
#define OFFB_MDH ((size_t)4489216)        // Dh[64][160] = 20480 B
#define OFFB_Y2  ((size_t)(8u<<20))       // 8*512*4480 bf16 = 35MB
#define OFFB_Y1  ((size_t)(45u<<20))      // 8*4480*512 bf16 = 35MB

static __device__ __forceinline__ u16 f2b(float f) {
  union { float f; u32 u; } v; v.f = f;
  u32 u = v.u;
  return (u16)((u + 0x7fffu + ((u >> 16) & 1u)) >> 16);
}
static __device__ __forceinline__ float b2f(u16 h) {
  union { u32 u; float f; } v; v.u = ((u32)h) << 16; return v.f;
}
// address-derived XOR swizzle: flips byte bits 4..6 from bits 9..11 (bijective;
// preserves 16B-chunk contiguity and alignment for all naturally-aligned <=16B accesses)
static __device__ __forceinline__ u32 swzb(u32 byteoff) {
  return byteoff ^ (((byteoff >> 9) & 7u) << 4);
}

// ---------- float filter construction ----------
static __device__ float bessel_i0f(float x) {
  float t = x * 0.5f, t2 = t * t;
  float term = 1.f, sum = 1.f;
  for (int k = 1; k < 32; k++) {
    term *= t2 / ((float)k * (float)k);
    sum += term;
    if (term < 1e-8f * sum) break;
  }
  return sum;
}
static __device__ void firwin_devf(int numtaps, float cutoff, float width, float fs, float* out) {
  float nyq = fs * 0.5f;
  float atten = 2.285f * (numtaps - 1) * 3.14159265358979f * (width / nyq) + 7.95f;
  float beta;
  if (atten > 50.f) beta = 0.1102f * (atten - 8.7f);
  else if (atten > 21.f) beta = 0.5842f * powf(atten - 21.f, 0.4f) + 0.07886f * (atten - 21.f);
  else beta = 0.f;
  float c = cutoff / nyq;
  float i0b = bessel_i0f(beta);
  float h[16]; float s = 0.f;
  for (int n = 0; n < numtaps; n++) {
    float m = n - (numtaps - 1) * 0.5f;
    float x = c * m;
    float pix = 3.14159265358979f * x;
    float snc = (x == 0.f) ? 1.f : __sinf(pix) / pix;
    float r = 2.f * n / (float)(numtaps - 1) - 1.f;
    float arg = 1.f - r * r; if (arg < 0.f) arg = 0.f;
    float kais = bessel_i0f(beta * sqrtf(arg)) / i0b;
    h[n] = c * snc * kais; s += h[n];
  }
  for (int n = 0; n < numtaps; n++) out[n] = h[n] / s;
}

// ---------- K1: filters + gauss + SIREN h3 + MFMA filter matrices ----------
__global__ void k_setup(const float* __restrict__ sw0, const float* __restrict__ sb0,
                        const float* __restrict__ sw1, const float* __restrict__ sb1,
                        const float* __restrict__ sw2, const float* __restrict__ sb2,
                        float* __restrict__ ws) {
  __shared__ float hA[2304], hB[2304];
  int t = threadIdx.x;
  if (t == 0) {
    firwin_devf(12, 32.f, 2.f * 32.f * 0.41421356237309515f, 128.f, ws + FOFF_FUP);
  }
  if (t == 64) {
    float kc = 1.5f;
    firwin_devf(4, kc, 2.f * kc * 0.41421356237309515f, kc * 2.f * 1.0717734625362931f, ws + FOFF_KG);
  }
  if (t == 128) {
    float s2 = 0.5f;
    float gk[3];
    for (int k = 0; k < 3; k++) {
      float kn = (float)(k - 1);
      gk[k] = expf(-kn * kn / (2.f * s2)) / sqrtf(2.f * 3.14159265358979f * s2);
    }
    for (int i = 0; i < 3; i++)
      for (int j = 0; j < 3; j++)
        ws[FOFF_GAUSS + i * 3 + j] = sqrtf(gk[i] * gk[j]) * 2.f;
  }
  if (t >= 192 && t < 200) ws[FOFF_PART + t - 192] = 0.f;
  for (int idx = t; idx < 2304; idx += 256) {
    int p = idx >> 6, u = idx & 63;
    float gx = (2.f * (p % 6) + 1.f) / 6.f - 1.f;
    float gy = (2.f * (p / 6) + 1.f) / 6.f - 1.f;
    hA[idx] = sinf(30.f * (gx * sw0[u] + gy * sw0[64 + u] + sb0[u]));
  }
  __syncthreads();   // fu now visible to all threads
  {
    float fuv[12];
    #pragma unroll
    for (int i = 0; i < 12; i++) fuv[i] = ws[FOFF_FUP + i];
    char* wsb = (char*)ws;
    u16* muv = (u16*)(wsb + OFFB_MUV);
    u16* muh = (u16*)(wsb + OFFB_MUH);
    u16* mdv = (u16*)(wsb + OFFB_MDV);
    u16* mdh = (u16*)(wsb + OFFB_MDH);
    for (int i = t; i < 48 * 32; i += 256) {       // Uv[r][s]
      int r = i >> 5, s = i & 31;
      float v = 0.f;
      if (r < 42 && s < 26) {
        int d = (r >> 1) + 5 - s;
        if (d >= 0 && d <= 5) v = fuv[2 * d + (r & 1)];
      }
      muv[i] = f2b(v);
    }
    for (int i = t; i < 144 * 96; i += 256) {      // Uh[n][j]
      int n = i / 96, j = i - n * 96;
      float v = 0.f;
      if (n < 138 && j < 66) {
        int k = (n >> 1) + 1 - j;
        if (k >= 0 && k <= 5) v = fuv[2 * k + (n & 1)];
      }
      muh[i] = f2b(v);
    }
    for (int i = t; i < 16 * 64; i += 256) {       // Dv[R][ar]
      int R = i >> 6, ar = i & 63;
      float v = 0.f;
      if (ar < 42) {
        int q = ar - 2 * R;
        if (q >= 0 && q <= 11) v = fuv[11 - q];
      }
      mdv[i] = f2b(v);
    }
    for (int i = t; i < 64 * 160; i += 256) {      // Dh[ox][ac]
      int ox = i / 160, ac = i - ox * 160;
      float v = 0.f;
      if (ac < 138) {
        int q = ac - 2 * ox;
        if (q >= 0 && q <= 11) v = fuv[11 - q];
      }
      mdh[i] = f2b(v);
    }
  }
  for (int idx = t; idx < 2304; idx += 256) {
    int p = idx >> 6, u = idx & 63;
    float acc = sb1[u];
    for (int v = 0; v < 64; v++) acc += hA[p * 64 + v] * sw1[v * 64 + u];
    hB[idx] = sinf(acc);
  }
  __syncthreads();
  for (int idx = t; idx < 2304; idx += 256) {
    int p = idx >> 6, u = idx & 63;
    float acc = sb2[u];
    for (int v = 0; v < 64; v++) acc += hB[p * 64 + v] * sw2[v * 64 + u];
    ws[FOFF_H3 + idx] = sinf(acc);
  }
}

// ---------- K2+K3 merged ----------
__global__ void k_stkw(const float* __restrict__ w, const float* __restrict__ aw,
                       const float* __restrict__ ab,
                       const float* __restrict__ w3, const float* __restrict__ b3,
                       const float* __restrict__ kscale, const float* __restrict__ emap,
                       float* __restrict__ ws) {
  __shared__ __align__(16) char sm[18944];
  int t = threadIdx.x;
  if (blockIdx.x < 64) {
    float* wl  = (float*)sm;          // [512]
    float* red = (float*)(sm + 2048); // [256]
    int b = blockIdx.x >> 3, j0 = (blockIdx.x & 7) * 64;
    wl[t] = w[b * 512 + t]; wl[t + 256] = w[b * 512 + 256 + t];
    __syncthreads();
    int j = j0 + (t & 63), kq = t >> 6;
    const f32x4* ar = (const f32x4*)(aw + (size_t)j * 512 + kq * 128);
    const f32x4* wv = (const f32x4*)(wl + kq * 128);
    float acc = 0.f;
    for (int k = 0; k < 32; k++) {
      f32x4 a = ar[k], c = wv[k];
      acc += a[0] * c[0] + a[1] * c[1] + a[2] * c[2] + a[3] * c[3];
    }
    red[t] = acc; __syncthreads();
    if (t < 64) {
      float sv = (red[t] + red[t + 64] + red[t + 128] + red[t + 192]) * 0.04419417382415922f + ab[j0 + t];
      ws[FOFF_STYLES + b * 512 + j0 + t] = sv;
      float p = sv * sv;
      for (int m = 32; m; m >>= 1) p += __shfl_xor(p, m);
      if (t == 0) atomicAdd(&ws[FOFF_PART + b], p);
    }
  } else {
    float* h3l = (float*)sm;            // [2304]
    float (*kw6)[37] = (float(*)[37])(sm + 9216);  // [64][37]
    int c0 = (blockIdx.x - 64) * 64;
    for (int i = t; i < 2304; i += 256) h3l[i] = ws[FOFF_H3 + i];
    __syncthreads();
    int cl = t & 63, pg = t >> 6;
    int c = c0 + cl;
    float acc[9];
    #pragma unroll
    for (int q = 0; q < 9; q++) acc[q] = b3[c];
    for (int v = 0; v < 64; v++) {
      float wv = w3[v * 512 + c];
      #pragma unroll
      for (int q = 0; q < 9; q++) acc[q] += h3l[(pg * 9 + q) * 64 + v] * wv;
    }
    float sc = 2.f / (1.f + expf(-kscale[c] * 0.1f));
    #pragma unroll
    for (int q = 0; q < 9; q++) kw6[cl][pg * 9 + q] = acc[q] * sc;
    __syncthreads();
    if (t < 64) {
      float kg[4];
      #pragma unroll
      for (int i = 0; i < 4; i++) kg[i] = ws[FOFF_KG + i];
      float pre[9];
      for (int u = 0; u < 3; u++)
        for (int vv = 0; vv < 3; vv++) {
          float s = 0.f;
          for (int t1 = 0; t1 < 4; t1++) {
            int a = 2 * u + t1 - 1;
            if (a < 0 || a > 5) continue;
            for (int t2 = 0; t2 < 4; t2++) {
              int bb = 2 * vv + t2 - 1;
              if (bb < 0 || bb > 5) continue;
              s += kg[3 - t1] * kg[3 - t2] * kw6[t][a * 6 + bb];
            }
          }
          pre[u * 3 + vv] = s;
        }
      float m = 0.f;
      #pragma unroll
      for (int q = 0; q < 9; q++) m += pre[q];
      m *= (1.f / 9.f);
      float ms = 0.f;
      #pragma unroll
      for (int q = 0; q < 9; q++) { pre[q] -= m; ms += pre[q] * pre[q]; }
      ms *= (1.f / 9.f);
      float r = 1.f / sqrtf(ms);
      float re = 1.f / sqrtf(emap[0]);
      #pragma unroll
      for (int q = 0; q < 9; q++)
        ws[FOFF_KK + q * 512 + (c0 + t)] = pre[q] * r * ws[FOFF_GAUSS + q] * re;
    }
  }
}

// ---------- K4 v2: modulated weights ----------
__global__ void k_wb(const float* __restrict__ sw, const float* __restrict__ ws,
                     u16* __restrict__ wb) {
  int wv = threadIdx.x >> 6, lane = threadIdx.x & 63;
  int o = blockIdx.x * 4 + wv, b = blockIdx.y;
  float ssum = 0.f;
  #pragma unroll
  for (int i = 0; i < 8; i++) ssum += ws[FOFF_PART + i];
  float rsn = 1.f / sqrtf(ssum * (1.f / 4096.f));
  float swv[8], stv[8];
  float s2 = 0.f;
  #pragma unroll
  for (int q = 0; q < 8; q++) {
    int i = lane + q * 64;
    swv[q] = sw[(size_t)o * 512 + i];
    stv[q] = ws[FOFF_STYLES + b * 512 + i];
    s2 += swv[q] * swv[q];
  }
  for (int m = 32; m; m >>= 1) s2 += __shfl_xor(s2, m);
  float r1 = 1.f / sqrtf(s2 * (1.f / 512.f));
  float tv[8]; float t2 = 0.f;
  #pragma unroll
  for (int q = 0; q < 8; q++) { tv[q] = swv[q] * r1 * stv[q] * rsn; t2 += tv[q] * tv[q]; }
  for (int m = 32; m; m >>= 1) t2 += __shfl_xor(t2, m);
  float r2 = 1.f / sqrtf(t2 + 1e-8f);
  #pragma unroll
  for (int q = 0; q < 8; q++)
    wb[((size_t)b * 512 + o) * 512 + lane + q * 64] = f2b(tv[q] * r2);
}

// ---------- K5+K6 fused: transpose-cast + depthwise 3x3 ----------
__global__ void k_tdw(const float* __restrict__ x, const float* __restrict__ ws,
                      u16* __restrict__ y1) {
  int h = blockIdx.x, cb = blockIdx.y, b = blockIdx.z;
  int c0 = cb * 64, t = threadIdx.x;
  if (h == 66) {
    u32* dst = (u32*)y1;
    for (int idx = t; idx < 124 * 32; idx += 256) {
      int row = idx >> 5, col = idx & 31;
      dst[((size_t)b * 4480 + 4356 + row) * 256 + (c0 >> 1) + col] = 0u;
    }
    return;
  }
  __shared__ u16 xl[3 * 68 * 64];
  for (int idx = t; idx < 3 * 4 * 64; idx += 256) {
    int i = idx >> 8, r = idx & 255;
    int wsl = r >> 6; wsl = (wsl < 2) ? wsl : (64 + wsl);
    xl[i * 4352 + wsl * 64 + (r & 63)] = 0;
  }
  for (int slot = t; slot < 768; slot += 256) {
    int c = slot & 63, ri = slot >> 6;
    int i = ri >> 2, q = ri & 3;
    int ih = h - 2 + i;
    u16* dst = &xl[i * 4352 + (2 + q * 16) * 64 + c];
    if (ih >= 0 && ih < 64) {
      const float* xp = x + ((size_t)(b * 512 + c0 + c)) * 4096 + ih * 64 + q * 16;
      #pragma unroll
      for (int k = 0; k < 16; k++) dst[k * 64] = f2b(xp[k]);
    } else {
      #pragma unroll
      for (int k = 0; k < 16; k++) dst[k * 64] = 0;
    }
  }
  __syncthreads();
  int c2i = t & 31, wg = t >> 5;
  int c2 = 2 * c2i;
  float2 kk[9];
  #pragma unroll
  for (int q = 0; q < 9; q++) kk[q] = *(const float2*)&ws[FOFF_KK + q * 512 + c0 + c2];
  for (int w_ = wg; w_ < 66; w_ += 8) {
    float a0 = 0.f, a1 = 0.f;
    #pragma unroll
    for (int i = 0; i < 3; i++) {
      #pragma unroll
      for (int j = 0; j < 3; j++) {
        u32 xv = *(const u32*)&xl[i * 4352 + (w_ + j) * 64 + c2];
        float2 kv = kk[i * 3 + j];
        a0 += kv.x * b2f((u16)xv);
        a1 += kv.y * b2f((u16)(xv >> 16));
      }
    }
    ((u32*)y1)[(((size_t)b * 4480 + h * 66 + w_) * 512 + c0 + c2) >> 1] =
        (u32)f2b(a0) | ((u32)f2b(a1) << 16);
  }
}

// ---------- K7: batched GEMM, XCD-aware remap ----------
__launch_bounds__(256, 4)
__global__ void k_gemm(const u16* __restrict__ wbm, const u16* __restrict__ y1,
                       const float* __restrict__ bias, u16* __restrict__ y2) {
  int lid = blockIdx.x + 35 * (blockIdx.y + (blockIdx.z << 2));
  int b  = lid & 7;
  int s_ = lid >> 3;
  int mt = s_ & 3;
  int nt = s_ >> 2;
  int t = threadIdx.x, lane = t & 63, wv = t >> 6;
  int wm = wv >> 1, wn = wv & 1;
  __shared__ u16 Al[4096];
  __shared__ u16 Bl[4096];
  f32x4 acc[4][4];
  #pragma unroll
  for (int i = 0; i < 4; i++)
    #pragma unroll
    for (int j = 0; j < 4; j++)
      acc[i][j] = (f32x4){0.f, 0.f, 0.f, 0.f};

  const size_t Abase = (size_t)b * 512 + mt * 128;
  const size_t Bbase = (size_t)b * 4480 + nt * 128;
  int lrow = lane >> 2, dch = lane & 3;
  int cp = lane >> 4;

  for (int ks = 0; ks < 16; ks++) {
    int k0 = ks * 32;
    __syncthreads();
    #pragma unroll
    for (int half = 0; half < 2; half++) {
      int rbase = half * 64 + wv * 16;
      int row = rbase + lrow;
      int gch = dch ^ ((row >> 1) & 3);
      const u16* ga = wbm + (Abase + row) * 512 + k0 + gch * 8;
      const u16* gb = y1 + (Bbase + row) * 512 + k0 + gch * 8;
      __builtin_amdgcn_global_load_lds((const gu32*)ga, (lu32*)&Al[rbase * 32], 16, 0, 0);
      __builtin_amdgcn_global_load_lds((const gu32*)gb, (lu32*)&Bl[rbase * 32], 16, 0, 0);
    }
    asm volatile("s_waitcnt vmcnt(0)" ::: "memory");
    __syncthreads();
    bf16x8 af[4], bfr[4];
    #pragma unroll
    for (int mi = 0; mi < 4; mi++) {
      int row = wm * 64 + mi * 16 + (lane & 15);
      af[mi] = *(const bf16x8*)&Al[row * 32 + ((cp ^ ((row >> 1) & 3)) * 8)];
    }
    #pragma unroll
    for (int ni = 0; ni < 4; ni++) {
      int row = wn * 64 + ni * 16 + (lane & 15);
      bfr[ni] = *(const bf16x8*)&Bl[row * 32 + ((cp ^ ((row >> 1) & 3)) * 8)];
    }
    #pragma unroll
    for (int mi = 0; mi < 4; mi++)
      #pragma unroll
      for (int ni = 0; ni < 4; ni++)
        acc[mi][ni] = __builtin_amdgcn_mfma_f32_16x16x32_bf16(af[mi], bfr[ni], acc[mi][ni], 0, 0, 0);
  }
  int col0 = nt * 128 + wn * 64 + (lane & 15);
  int rb = (lane >> 4) * 4;
  #pragma unroll
  for (int mi = 0; mi < 4; mi++) {
    #pragma unroll
    for (int j = 0; j < 4; j++) {
      int o = mt * 128 + wm * 64 + mi * 16 + rb + j;
      float bv = bias[o];
      size_t rowoff = ((size_t)b * 512 + o) * 4480;
      #pragma unroll
      for (int ni = 0; ni < 4; ni++)
        y2[rowoff + col0 + ni * 16] = f2b(acc[mi][ni][j] + bv);
    }
  }
}

// ---------- K8 v14: v13 structure + address-derived XOR swizzle on all LDS accesses ----------
// Regions (byte): @0 Yt[80][40] (6400) / Atw 4x[16][72] (9216, aliases Yt after S1)
//                 @9216 T1u[48][104] (9984) | @19200 T3u[16][168] (5376). 24576 B total.
// Every LDS byte address goes through swzb() (same bijection on write and read).
__launch_bounds__(256, 6)
__global__ void k_updown(const u16* __restrict__ y2,
                         const u16* __restrict__ muv, const u16* __restrict__ muh,
                         const u16* __restrict__ mdv, const u16* __restrict__ mdh,
                         float* __restrict__ out) {
  int g = blockIdx.x, o = blockIdx.y, b = blockIdx.z;
  int t = threadIdx.x, lane = t & 63, wv = t >> 6;
  int l15 = lane & 15, cp = lane >> 4, rb = cp * 4;
  __shared__ __align__(16) char smem[24576];
  const u32 atwb = (u32)wv * 2304;
  const int out_r0 = g * 16;
  const int yrow0 = out_r0 - 4;
  const u16* plane = y2 + ((size_t)b * 512 + o) * 4480;

  // blanket zero all 24576 B (swizzle is a bijection; zeroing linear == zeroing swizzled)
  for (int i = t; i < 1536; i += 256) ((float4*)smem)[i] = make_float4(0.f, 0.f, 0.f, 0.f);
  __syncthreads();
  // stage Y transposed: Yt[j][s] = y[yrow0+s][j]   (u16 at byte (j*40+s)*2)
  for (int idx = t; idx < 26 * 66; idx += 256) {
    int s = idx / 66, j = idx - 66 * s;
    int grow = yrow0 + s;
    u16 v = 0;
    if (grow >= 0 && grow < 66) v = plane[(size_t)grow * 66 + j];
    *(u16*)(smem + swzb((u32)(j * 40 + s) * 2)) = v;
  }
  __syncthreads();

  // S1: T1(48x80) = Uv(48x32) x Yt^T   (1 k-step)
  __builtin_amdgcn_s_setprio(1);
  for (int tau = wv; tau < 15; tau += 4) {
    int mi = tau / 5, ni = tau - mi * 5;
    bf16x8 a = *(const bf16x8*)&muv[(mi * 16 + l15) * 32 + cp * 8];
    bf16x8 bfr = *(const bf16x8*)(smem + swzb((u32)((ni * 16 + l15) * 40 + cp * 8) * 2));
    f32x4 acc = (f32x4){0.f, 0.f, 0.f, 0.f};
    acc = __builtin_amdgcn_mfma_f32_16x16x32_bf16(a, bfr, acc, 0, 0, 0);
    #pragma unroll
    for (int j = 0; j < 4; j++)
      *(u16*)(smem + swzb(9216u + (u32)((mi * 16 + rb + j) * 104 + ni * 16 + l15) * 2)) = f2b(acc[j]);
  }
  __builtin_amdgcn_s_setprio(0);
  __syncthreads();

  // Fused S2+S3 per ni (wave-local):
  __builtin_amdgcn_s_setprio(1);
  {
    bf16x8 a0 = *(const bf16x8*)&mdv[l15 * 64 + cp * 8];
    bf16x8 a1 = *(const bf16x8*)&mdv[l15 * 64 + 32 + cp * 8];
    for (int ni = wv; ni < 9; ni += 4) {
      bf16x8 bh[3];
      #pragma unroll
      for (int ks = 0; ks < 3; ks++)
        bh[ks] = *(const bf16x8*)&muh[(ni * 16 + l15) * 96 + ks * 32 + cp * 8];
      #pragma unroll
      for (int mi = 0; mi < 3; mi++) {
        f32x4 acc = (f32x4){0.f, 0.f, 0.f, 0.f};
        #pragma unroll
        for (int ks = 0; ks < 3; ks++) {
          bf16x8 a = *(const bf16x8*)(smem + swzb(9216u + (u32)((mi * 16 + l15) * 104 + ks * 32 + cp * 8) * 2));
          acc = __builtin_amdgcn_mfma_f32_16x16x32_bf16(a, bh[ks], acc, 0, 0, 0);
        }
        u16 pv[4];
        #pragma unroll
        for (int j = 0; j < 4; j++) {
          float x = acc[j];
          x = fmaxf(x, 0.2f * x) * 5.65685424949238f;
          x = fminf(fmaxf(x, -256.f), 256.f);
          pv[j] = f2b(x);
        }
        u32 lo = (u32)pv[0] | ((u32)pv[1] << 16);
        u32 hi = (u32)pv[2] | ((u32)pv[3] << 16);
        *(uint2*)(smem + swzb(atwb + (u32)(l15 * 72 + mi * 16 + rb) * 2)) = make_uint2(lo, hi);
      }
      asm volatile("s_waitcnt lgkmcnt(0)" ::: "memory");  // wave-local RAW fence
      f32x4 acc3 = (f32x4){0.f, 0.f, 0.f, 0.f};
      bf16x8 b0 = *(const bf16x8*)(smem + swzb(atwb + (u32)(l15 * 72 + cp * 8) * 2));
      acc3 = __builtin_amdgcn_mfma_f32_16x16x32_bf16(a0, b0, acc3, 0, 0, 0);
      bf16x8 b1 = *(const bf16x8*)(smem + swzb(atwb + (u32)(l15 * 72 + 32 + cp * 8) * 2));
      acc3 = __builtin_amdgcn_mfma_f32_16x16x32_bf16(a1, b1, acc3, 0, 0, 0);
      #pragma unroll
      for (int j = 0; j < 4; j++)
        *(u16*)(smem + swzb(19200u + (u32)((rb + j) * 168 + ni * 16 + l15) * 2)) = f2b(acc3[j]);
    }
  }
  __builtin_amdgcn_s_setprio(0);
  __syncthreads();

  // S4: OUT(16x64) = T3(16x160) x Dh^T  (5 k-steps), wave ni = wv
  {
    __builtin_amdgcn_s_setprio(1);
    f32x4 acc = (f32x4){0.f, 0.f, 0.f, 0.f};
    #pragma unroll
    for (int ks = 0; ks < 5; ks++) {
      bf16x8 a = *(const bf16x8*)(smem + swzb(19200u + (u32)(l15 * 168 + ks * 32 + cp * 8) * 2));
      bf16x8 bfr = *(const bf16x8*)&mdh[(wv * 16 + l15) * 160 + ks * 32 + cp * 8];
      acc = __builtin_amdgcn_mfma_f32_16x16x32_bf16(a, bfr, acc, 0, 0, 0);
    }
    __builtin_amdgcn_s_setprio(0);
    float* op = out + (((size_t)b * 512 + o) * 64 + out_r0) * 64;
    #pragma unroll
    for (int j = 0; j < 4; j++)
      op[(rb + j) * 64 + wv * 16 + l15] = acc[j];
  }
}

extern "C" void kernel_launch(void* const* d_in, const int* in_sizes, int n_in,
                              void* d_out, int out_size, void* d_ws, size_t ws_size,
                              hipStream_t stream) {
  const float* x     = (const float*)d_in[0];
  const float* w     = (const float*)d_in[1];
  const float* aw    = (const float*)d_in[2];
  const float* ab    = (const float*)d_in[3];
  const float* swgt  = (const float*)d_in[4];
  const float* bias  = (const float*)d_in[5];
  const float* sw0   = (const float*)d_in[6];
  const float* sb0   = (const float*)d_in[7];
  const float* sw1   = (const float*)d_in[8];
  const float* sb1   = (const float*)d_in[9];
  const float* sw2   = (const float*)d_in[10];
  const float* sb2   = (const float*)d_in[11];
  const float* sw3   = (const float*)d_in[12];
  const float* sb3   = (const float*)d_in[13];
  const float* kscl  = (const float*)d_in[14];
  const float* ema   = (const float*)d_in[15];

  float* ws  = (float*)d_ws;
  char*  wsb = (char*)d_ws;
  u16* wbp = (u16*)(wsb + OFFB_WB);
  u16* y2  = (u16*)(wsb + OFFB_Y2);
  u16* y1  = (u16*)(wsb + OFFB_Y1);
  u16* muv = (u16*)(wsb + OFFB_MUV);
  u16* muh = (u16*)(wsb + OFFB_MUH);
  u16* mdv = (u16*)(wsb + OFFB_MDV);
  u16* mdh = (u16*)(wsb + OFFB_MDH);

  k_setup<<<dim3(1), dim3(256), 0, stream>>>(sw0, sb0, sw1, sb1, sw2, sb2, ws);
  k_stkw<<<dim3(72), dim3(256), 0, stream>>>(w, aw, ab, sw3, sb3, kscl, ema, ws);
  k_wb<<<dim3(128, 8), dim3(256), 0, stream>>>(swgt, ws, wbp);
  k_tdw<<<dim3(67, 8, 8), dim3(256), 0, stream>>>(x, ws, y1);
  k_gemm<<<dim3(35, 4, 8), dim3(256), 0, stream>>>(wbp, y1, bias, y2);
  k_updown<<<dim3(4, 512, 8), dim3(256), 0, stream>>>(y2, muv, muh, mdv, mdh, (float*)d_out);
}

// Round 21
// 242.563 us; speedup vs baseline: 1.0069x; 1.0069x over previous
//
#include <hip/hip_runtime.h>
#include <stdint.h>
#include <math.h>

typedef uint16_t u16; typedef uint32_t u32;
typedef __bf16 bf16x8 __attribute__((ext_vector_type(8)));
typedef float  f32x4  __attribute__((ext_vector_type(4)));
typedef u32 __attribute__((address_space(1))) gu32;
typedef u32 __attribute__((address_space(3))) lu32;

// ---- ws layout ----
#define FOFF_FUP    0        // 12 floats (up==down filter)
#define FOFF_KG     16       // 4
#define FOFF_GAUSS  24       // 9
#define FOFF_PART   40       // 8 per-batch styles^2 partial sums
#define FOFF_H3     48       // 36*64
#define FOFF_STYLES 2368     // 8*512
#define FOFF_KK     6464     // 9*512  (tap-major)
#define OFFB_WB  ((size_t)65536)          // 8*512*512 bf16 = 4MB (ends 4259840)
#define OFFB_MUV ((size_t)4456448)        // Uv[48][32]  = 3072 B
#define OFFB_MUH ((size_t)4459520)        // Uh[144][96] = 27648 B
#define OFFB_MDV ((size_t)4487168)        // Dv[16][64]  = 2048 B
#define OFFB_MDH ((size_t)4489216)        // Dh[64][160] = 20480 B
#define OFFB_Y2  ((size_t)(8u<<20))       // 8*512*4480 bf16 = 35MB
#define OFFB_Y1  ((size_t)(45u<<20))      // 8*4480*512 bf16 = 35MB

static __device__ __forceinline__ u16 f2b(float f) {
  union { float f; u32 u; } v; v.f = f;
  u32 u = v.u;
  return (u16)((u + 0x7fffu + ((u >> 16) & 1u)) >> 16);
}
static __device__ __forceinline__ float b2f(u16 h) {
  union { u32 u; float f; } v; v.u = ((u32)h) << 16; return v.f;
}

// ---------- float filter construction ----------
static __device__ float bessel_i0f(float x) {
  float t = x * 0.5f, t2 = t * t;
  float term = 1.f, sum = 1.f;
  for (int k = 1; k < 32; k++) {
    term *= t2 / ((float)k * (float)k);
    sum += term;
    if (term < 1e-8f * sum) break;
  }
  return sum;
}
static __device__ void firwin_devf(int numtaps, float cutoff, float width, float fs, float* out) {
  float nyq = fs * 0.5f;
  float atten = 2.285f * (numtaps - 1) * 3.14159265358979f * (width / nyq) + 7.95f;
  float beta;
  if (atten > 50.f) beta = 0.1102f * (atten - 8.7f);
  else if (atten > 21.f) beta = 0.5842f * powf(atten - 21.f, 0.4f) + 0.07886f * (atten - 21.f);
  else beta = 0.f;
  float c = cutoff / nyq;
  float i0b = bessel_i0f(beta);
  float h[16]; float s = 0.f;
  for (int n = 0; n < numtaps; n++) {
    float m = n - (numtaps - 1) * 0.5f;
    float x = c * m;
    float pix = 3.14159265358979f * x;
    float snc = (x == 0.f) ? 1.f : __sinf(pix) / pix;
    float r = 2.f * n / (float)(numtaps - 1) - 1.f;
    float arg = 1.f - r * r; if (arg < 0.f) arg = 0.f;
    float kais = bessel_i0f(beta * sqrtf(arg)) / i0b;
    h[n] = c * snc * kais; s += h[n];
  }
  for (int n = 0; n < numtaps; n++) out[n] = h[n] / s;
}

// ---------- K1: filters + gauss + SIREN h3 + MFMA filter matrices ----------
__global__ void k_setup(const float* __restrict__ sw0, const float* __restrict__ sb0,
                        const float* __restrict__ sw1, const float* __restrict__ sb1,
                        const float* __restrict__ sw2, const float* __restrict__ sb2,
                        float* __restrict__ ws) {
  __shared__ float hA[2304], hB[2304];
  int t = threadIdx.x;
  if (t == 0) {
    firwin_devf(12, 32.f, 2.f * 32.f * 0.41421356237309515f, 128.f, ws + FOFF_FUP);
  }
  if (t == 64) {
    float kc = 1.5f;
    firwin_devf(4, kc, 2.f * kc * 0.41421356237309515f, kc * 2.f * 1.0717734625362931f, ws + FOFF_KG);
  }
  if (t == 128) {
    float s2 = 0.5f;
    float gk[3];
    for (int k = 0; k < 3; k++) {
      float kn = (float)(k - 1);
      gk[k] = expf(-kn * kn / (2.f * s2)) / sqrtf(2.f * 3.14159265358979f * s2);
    }
    for (int i = 0; i < 3; i++)
      for (int j = 0; j < 3; j++)
        ws[FOFF_GAUSS + i * 3 + j] = sqrtf(gk[i] * gk[j]) * 2.f;
  }
  if (t >= 192 && t < 200) ws[FOFF_PART + t - 192] = 0.f;
  for (int idx = t; idx < 2304; idx += 256) {
    int p = idx >> 6, u = idx & 63;
    float gx = (2.f * (p % 6) + 1.f) / 6.f - 1.f;
    float gy = (2.f * (p / 6) + 1.f) / 6.f - 1.f;
    hA[idx] = sinf(30.f * (gx * sw0[u] + gy * sw0[64 + u] + sb0[u]));
  }
  __syncthreads();   // fu now visible to all threads
  {
    float fuv[12];
    #pragma unroll
    for (int i = 0; i < 12; i++) fuv[i] = ws[FOFF_FUP + i];
    char* wsb = (char*)ws;
    u16* muv = (u16*)(wsb + OFFB_MUV);
    u16* muh = (u16*)(wsb + OFFB_MUH);
    u16* mdv = (u16*)(wsb + OFFB_MDV);
    u16* mdh = (u16*)(wsb + OFFB_MDH);
    for (int i = t; i < 48 * 32; i += 256) {       // Uv[r][s]
      int r = i >> 5, s = i & 31;
      float v = 0.f;
      if (r < 42 && s < 26) {
        int d = (r >> 1) + 5 - s;
        if (d >= 0 && d <= 5) v = fuv[2 * d + (r & 1)];
      }
      muv[i] = f2b(v);
    }
    for (int i = t; i < 144 * 96; i += 256) {      // Uh[n][j]
      int n = i / 96, j = i - n * 96;
      float v = 0.f;
      if (n < 138 && j < 66) {
        int k = (n >> 1) + 1 - j;
        if (k >= 0 && k <= 5) v = fuv[2 * k + (n & 1)];
      }
      muh[i] = f2b(v);
    }
    for (int i = t; i < 16 * 64; i += 256) {       // Dv[R][ar]
      int R = i >> 6, ar = i & 63;
      float v = 0.f;
      if (ar < 42) {
        int q = ar - 2 * R;
        if (q >= 0 && q <= 11) v = fuv[11 - q];
      }
      mdv[i] = f2b(v);
    }
    for (int i = t; i < 64 * 160; i += 256) {      // Dh[ox][ac]
      int ox = i / 160, ac = i - ox * 160;
      float v = 0.f;
      if (ac < 138) {
        int q = ac - 2 * ox;
        if (q >= 0 && q <= 11) v = fuv[11 - q];
      }
      mdh[i] = f2b(v);
    }
  }
  for (int idx = t; idx < 2304; idx += 256) {
    int p = idx >> 6, u = idx & 63;
    float acc = sb1[u];
    for (int v = 0; v < 64; v++) acc += hA[p * 64 + v] * sw1[v * 64 + u];
    hB[idx] = sinf(acc);
  }
  __syncthreads();
  for (int idx = t; idx < 2304; idx += 256) {
    int p = idx >> 6, u = idx & 63;
    float acc = sb2[u];
    for (int v = 0; v < 64; v++) acc += hB[p * 64 + v] * sw2[v * 64 + u];
    ws[FOFF_H3 + idx] = sinf(acc);
  }
}

// ---------- K2+K3 merged ----------
__global__ void k_stkw(const float* __restrict__ w, const float* __restrict__ aw,
                       const float* __restrict__ ab,
                       const float* __restrict__ w3, const float* __restrict__ b3,
                       const float* __restrict__ kscale, const float* __restrict__ emap,
                       float* __restrict__ ws) {
  __shared__ __align__(16) char sm[18944];
  int t = threadIdx.x;
  if (blockIdx.x < 64) {
    float* wl  = (float*)sm;          // [512]
    float* red = (float*)(sm + 2048); // [256]
    int b = blockIdx.x >> 3, j0 = (blockIdx.x & 7) * 64;
    wl[t] = w[b * 512 + t]; wl[t + 256] = w[b * 512 + 256 + t];
    __syncthreads();
    int j = j0 + (t & 63), kq = t >> 6;
    const f32x4* ar = (const f32x4*)(aw + (size_t)j * 512 + kq * 128);
    const f32x4* wv = (const f32x4*)(wl + kq * 128);
    float acc = 0.f;
    for (int k = 0; k < 32; k++) {
      f32x4 a = ar[k], c = wv[k];
      acc += a[0] * c[0] + a[1] * c[1] + a[2] * c[2] + a[3] * c[3];
    }
    red[t] = acc; __syncthreads();
    if (t < 64) {
      float sv = (red[t] + red[t + 64] + red[t + 128] + red[t + 192]) * 0.04419417382415922f + ab[j0 + t];
      ws[FOFF_STYLES + b * 512 + j0 + t] = sv;
      float p = sv * sv;
      for (int m = 32; m; m >>= 1) p += __shfl_xor(p, m);
      if (t == 0) atomicAdd(&ws[FOFF_PART + b], p);
    }
  } else {
    float* h3l = (float*)sm;            // [2304]
    float (*kw6)[37] = (float(*)[37])(sm + 9216);  // [64][37]
    int c0 = (blockIdx.x - 64) * 64;
    for (int i = t; i < 2304; i += 256) h3l[i] = ws[FOFF_H3 + i];
    __syncthreads();
    int cl = t & 63, pg = t >> 6;
    int c = c0 + cl;
    float acc[9];
    #pragma unroll
    for (int q = 0; q < 9; q++) acc[q] = b3[c];
    for (int v = 0; v < 64; v++) {
      float wv = w3[v * 512 + c];
      #pragma unroll
      for (int q = 0; q < 9; q++) acc[q] += h3l[(pg * 9 + q) * 64 + v] * wv;
    }
    float sc = 2.f / (1.f + expf(-kscale[c] * 0.1f));
    #pragma unroll
    for (int q = 0; q < 9; q++) kw6[cl][pg * 9 + q] = acc[q] * sc;
    __syncthreads();
    if (t < 64) {
      float kg[4];
      #pragma unroll
      for (int i = 0; i < 4; i++) kg[i] = ws[FOFF_KG + i];
      float pre[9];
      for (int u = 0; u < 3; u++)
        for (int vv = 0; vv < 3; vv++) {
          float s = 0.f;
          for (int t1 = 0; t1 < 4; t1++) {
            int a = 2 * u + t1 - 1;
            if (a < 0 || a > 5) continue;
            for (int t2 = 0; t2 < 4; t2++) {
              int bb = 2 * vv + t2 - 1;
              if (bb < 0 || bb > 5) continue;
              s += kg[3 - t1] * kg[3 - t2] * kw6[t][a * 6 + bb];
            }
          }
          pre[u * 3 + vv] = s;
        }
      float m = 0.f;
      #pragma unroll
      for (int q = 0; q < 9; q++) m += pre[q];
      m *= (1.f / 9.f);
      float ms = 0.f;
      #pragma unroll
      for (int q = 0; q < 9; q++) { pre[q] -= m; ms += pre[q] * pre[q]; }
      ms *= (1.f / 9.f);
      float r = 1.f / sqrtf(ms);
      float re = 1.f / sqrtf(emap[0]);
      #pragma unroll
      for (int q = 0; q < 9; q++)
        ws[FOFF_KK + q * 512 + (c0 + t)] = pre[q] * r * ws[FOFF_GAUSS + q] * re;
    }
  }
}

// ---------- K4 v2: modulated weights ----------
__global__ void k_wb(const float* __restrict__ sw, const float* __restrict__ ws,
                     u16* __restrict__ wb) {
  int wv = threadIdx.x >> 6, lane = threadIdx.x & 63;
  int o = blockIdx.x * 4 + wv, b = blockIdx.y;
  float ssum = 0.f;
  #pragma unroll
  for (int i = 0; i < 8; i++) ssum += ws[FOFF_PART + i];
  float rsn = 1.f / sqrtf(ssum * (1.f / 4096.f));
  float swv[8], stv[8];
  float s2 = 0.f;
  #pragma unroll
  for (int q = 0; q < 8; q++) {
    int i = lane + q * 64;
    swv[q] = sw[(size_t)o * 512 + i];
    stv[q] = ws[FOFF_STYLES + b * 512 + i];
    s2 += swv[q] * swv[q];
  }
  for (int m = 32; m; m >>= 1) s2 += __shfl_xor(s2, m);
  float r1 = 1.f / sqrtf(s2 * (1.f / 512.f));
  float tv[8]; float t2 = 0.f;
  #pragma unroll
  for (int q = 0; q < 8; q++) { tv[q] = swv[q] * r1 * stv[q] * rsn; t2 += tv[q] * tv[q]; }
  for (int m = 32; m; m >>= 1) t2 += __shfl_xor(t2, m);
  float r2 = 1.f / sqrtf(t2 + 1e-8f);
  #pragma unroll
  for (int q = 0; q < 8; q++)
    wb[((size_t)b * 512 + o) * 512 + lane + q * 64] = f2b(tv[q] * r2);
}

// ---------- K5+K6 fused: transpose-cast + depthwise 3x3 ----------
__global__ void k_tdw(const float* __restrict__ x, const float* __restrict__ ws,
                      u16* __restrict__ y1) {
  int h = blockIdx.x, cb = blockIdx.y, b = blockIdx.z;
  int c0 = cb * 64, t = threadIdx.x;
  if (h == 66) {
    u32* dst = (u32*)y1;
    for (int idx = t; idx < 124 * 32; idx += 256) {
      int row = idx >> 5, col = idx & 31;
      dst[((size_t)b * 4480 + 4356 + row) * 256 + (c0 >> 1) + col] = 0u;
    }
    return;
  }
  __shared__ u16 xl[3 * 68 * 64];
  for (int idx = t; idx < 3 * 4 * 64; idx += 256) {
    int i = idx >> 8, r = idx & 255;
    int wsl = r >> 6; wsl = (wsl < 2) ? wsl : (64 + wsl);
    xl[i * 4352 + wsl * 64 + (r & 63)] = 0;
  }
  for (int slot = t; slot < 768; slot += 256) {
    int c = slot & 63, ri = slot >> 6;
    int i = ri >> 2, q = ri & 3;
    int ih = h - 2 + i;
    u16* dst = &xl[i * 4352 + (2 + q * 16) * 64 + c];
    if (ih >= 0 && ih < 64) {
      const float* xp = x + ((size_t)(b * 512 + c0 + c)) * 4096 + ih * 64 + q * 16;
      #pragma unroll
      for (int k = 0; k < 16; k++) dst[k * 64] = f2b(xp[k]);
    } else {
      #pragma unroll
      for (int k = 0; k < 16; k++) dst[k * 64] = 0;
    }
  }
  __syncthreads();
  int c2i = t & 31, wg = t >> 5;
  int c2 = 2 * c2i;
  float2 kk[9];
  #pragma unroll
  for (int q = 0; q < 9; q++) kk[q] = *(const float2*)&ws[FOFF_KK + q * 512 + c0 + c2];
  for (int w_ = wg; w_ < 66; w_ += 8) {
    float a0 = 0.f, a1 = 0.f;
    #pragma unroll
    for (int i = 0; i < 3; i++) {
      #pragma unroll
      for (int j = 0; j < 3; j++) {
        u32 xv = *(const u32*)&xl[i * 4352 + (w_ + j) * 64 + c2];
        float2 kv = kk[i * 3 + j];
        a0 += kv.x * b2f((u16)xv);
        a1 += kv.y * b2f((u16)(xv >> 16));
      }
    }
    ((u32*)y1)[(((size_t)b * 4480 + h * 66 + w_) * 512 + c0 + c2) >> 1] =
        (u32)f2b(a0) | ((u32)f2b(a1) << 16);
  }
}

// ---------- K7: batched GEMM, XCD-aware remap ----------
__launch_bounds__(256, 4)
__global__ void k_gemm(const u16* __restrict__ wbm, const u16* __restrict__ y1,
                       const float* __restrict__ bias, u16* __restrict__ y2) {
  int lid = blockIdx.x + 35 * (blockIdx.y + (blockIdx.z << 2));
  int b  = lid & 7;
  int s_ = lid >> 3;
  int mt = s_ & 3;
  int nt = s_ >> 2;
  int t = threadIdx.x, lane = t & 63, wv = t >> 6;
  int wm = wv >> 1, wn = wv & 1;
  __shared__ u16 Al[4096];
  __shared__ u16 Bl[4096];
  f32x4 acc[4][4];
  #pragma unroll
  for (int i = 0; i < 4; i++)
    #pragma unroll
    for (int j = 0; j < 4; j++)
      acc[i][j] = (f32x4){0.f, 0.f, 0.f, 0.f};

  const size_t Abase = (size_t)b * 512 + mt * 128;
  const size_t Bbase = (size_t)b * 4480 + nt * 128;
  int lrow = lane >> 2, dch = lane & 3;
  int cp = lane >> 4;

  for (int ks = 0; ks < 16; ks++) {
    int k0 = ks * 32;
    __syncthreads();
    #pragma unroll
    for (int half = 0; half < 2; half++) {
      int rbase = half * 64 + wv * 16;
      int row = rbase + lrow;
      int gch = dch ^ ((row >> 1) & 3);
      const u16* ga = wbm + (Abase + row) * 512 + k0 + gch * 8;
      const u16* gb = y1 + (Bbase + row) * 512 + k0 + gch * 8;
      __builtin_amdgcn_global_load_lds((const gu32*)ga, (lu32*)&Al[rbase * 32], 16, 0, 0);
      __builtin_amdgcn_global_load_lds((const gu32*)gb, (lu32*)&Bl[rbase * 32], 16, 0, 0);
    }
    asm volatile("s_waitcnt vmcnt(0)" ::: "memory");
    __syncthreads();
    bf16x8 af[4], bfr[4];
    #pragma unroll
    for (int mi = 0; mi < 4; mi++) {
      int row = wm * 64 + mi * 16 + (lane & 15);
      af[mi] = *(const bf16x8*)&Al[row * 32 + ((cp ^ ((row >> 1) & 3)) * 8)];
    }
    #pragma unroll
    for (int ni = 0; ni < 4; ni++) {
      int row = wn * 64 + ni * 16 + (lane & 15);
      bfr[ni] = *(const bf16x8*)&Bl[row * 32 + ((cp ^ ((row >> 1) & 3)) * 8)];
    }
    #pragma unroll
    for (int mi = 0; mi < 4; mi++)
      #pragma unroll
      for (int ni = 0; ni < 4; ni++)
        acc[mi][ni] = __builtin_amdgcn_mfma_f32_16x16x32_bf16(af[mi], bfr[ni], acc[mi][ni], 0, 0, 0);
  }
  int col0 = nt * 128 + wn * 64 + (lane & 15);
  int rb = (lane >> 4) * 4;
  #pragma unroll
  for (int mi = 0; mi < 4; mi++) {
    #pragma unroll
    for (int j = 0; j < 4; j++) {
      int o = mt * 128 + wm * 64 + mi * 16 + rb + j;
      float bv = bias[o];
      size_t rowoff = ((size_t)b * 512 + o) * 4480;
      #pragma unroll
      for (int ni = 0; ni < 4; ni++)
        y2[rowoff + col0 + ni * 16] = f2b(acc[mi][ni][j] + bv);
    }
  }
}

// ---------- K8 v13 (R19-verified 120.6us): S2+S3 fused via per-wave LDS scratch ----------
// Regions: @0 Yt[80][40] (6400B) / Atw 4x[16][72] (9216B) | @9216 T1u[48][104] (9984B) | @19200 T3u[16][168] (5376B)
__launch_bounds__(256, 6)
__global__ void k_updown(const u16* __restrict__ y2,
                         const u16* __restrict__ muv, const u16* __restrict__ muh,
                         const u16* __restrict__ mdv, const u16* __restrict__ mdh,
                         float* __restrict__ out) {
  int g = blockIdx.x, o = blockIdx.y, b = blockIdx.z;
  int t = threadIdx.x, lane = t & 63, wv = t >> 6;
  int l15 = lane & 15, cp = lane >> 4, rb = cp * 4;
  __shared__ __align__(16) char smem[24576];
  u16* Yt  = (u16*)smem;                        // [80][40] (dead after S1)
  u16* Atw = (u16*)(smem + (size_t)wv * 2304);  // per-wave [16][72] (aliases Yt region after S1)
  u16* T1u = (u16*)(smem + 9216);               // [48][104] (live through fused phase)
  u16* T3u = (u16*)(smem + 19200);              // [16][168] (own region)
  const int out_r0 = g * 16;
  const int yrow0 = out_r0 - 4;
  const u16* plane = y2 + ((size_t)b * 512 + o) * 4480;

  // blanket zero all 24576 B (pads + alias-stale cover)
  for (int i = t; i < 1536; i += 256) ((float4*)smem)[i] = make_float4(0.f, 0.f, 0.f, 0.f);
  __syncthreads();
  // stage Y transposed: Yt[j][s] = y[yrow0+s][j]
  for (int idx = t; idx < 26 * 66; idx += 256) {
    int s = idx / 66, j = idx - 66 * s;
    int grow = yrow0 + s;
    u16 v = 0;
    if (grow >= 0 && grow < 66) v = plane[(size_t)grow * 66 + j];
    Yt[j * 40 + s] = v;
  }
  __syncthreads();

  // S1: T1(48x80) = Uv(48x32) x Yt^T   (1 k-step)
  __builtin_amdgcn_s_setprio(1);
  for (int tau = wv; tau < 15; tau += 4) {
    int mi = tau / 5, ni = tau - mi * 5;
    bf16x8 a = *(const bf16x8*)&muv[(mi * 16 + l15) * 32 + cp * 8];
    bf16x8 bfr = *(const bf16x8*)&Yt[(ni * 16 + l15) * 40 + cp * 8];
    f32x4 acc = (f32x4){0.f, 0.f, 0.f, 0.f};
    acc = __builtin_amdgcn_mfma_f32_16x16x32_bf16(a, bfr, acc, 0, 0, 0);
    #pragma unroll
    for (int j = 0; j < 4; j++)
      T1u[(mi * 16 + rb + j) * 104 + ni * 16 + l15] = f2b(acc[j]);
  }
  __builtin_amdgcn_s_setprio(0);
  __syncthreads();

  // Fused S2+S3 per ni (wave-local, no block barrier):
  __builtin_amdgcn_s_setprio(1);
  {
    bf16x8 a0 = *(const bf16x8*)&mdv[l15 * 64 + cp * 8];
    bf16x8 a1 = *(const bf16x8*)&mdv[l15 * 64 + 32 + cp * 8];
    for (int ni = wv; ni < 9; ni += 4) {
      bf16x8 bh[3];
      #pragma unroll
      for (int ks = 0; ks < 3; ks++)
        bh[ks] = *(const bf16x8*)&muh[(ni * 16 + l15) * 96 + ks * 32 + cp * 8];
      #pragma unroll
      for (int mi = 0; mi < 3; mi++) {
        f32x4 acc = (f32x4){0.f, 0.f, 0.f, 0.f};
        #pragma unroll
        for (int ks = 0; ks < 3; ks++) {
          bf16x8 a = *(const bf16x8*)&T1u[(mi * 16 + l15) * 104 + ks * 32 + cp * 8];
          acc = __builtin_amdgcn_mfma_f32_16x16x32_bf16(a, bh[ks], acc, 0, 0, 0);
        }
        u16 pv[4];
        #pragma unroll
        for (int j = 0; j < 4; j++) {
          float x = acc[j];
          x = fmaxf(x, 0.2f * x) * 5.65685424949238f;
          x = fminf(fmaxf(x, -256.f), 256.f);
          pv[j] = f2b(x);
        }
        u32 lo = (u32)pv[0] | ((u32)pv[1] << 16);
        u32 hi = (u32)pv[2] | ((u32)pv[3] << 16);
        *(uint2*)&Atw[l15 * 72 + mi * 16 + rb] = make_uint2(lo, hi);
      }
      asm volatile("s_waitcnt lgkmcnt(0)" ::: "memory");  // wave-local RAW fence
      f32x4 acc3 = (f32x4){0.f, 0.f, 0.f, 0.f};
      bf16x8 b0 = *(const bf16x8*)&Atw[l15 * 72 + cp * 8];
      acc3 = __builtin_amdgcn_mfma_f32_16x16x32_bf16(a0, b0, acc3, 0, 0, 0);
      bf16x8 b1 = *(const bf16x8*)&Atw[l15 * 72 + 32 + cp * 8];
      acc3 = __builtin_amdgcn_mfma_f32_16x16x32_bf16(a1, b1, acc3, 0, 0, 0);
      #pragma unroll
      for (int j = 0; j < 4; j++)
        T3u[(rb + j) * 168 + ni * 16 + l15] = f2b(acc3[j]);
    }
  }
  __builtin_amdgcn_s_setprio(0);
  __syncthreads();

  // S4: OUT(16x64) = T3(16x160) x Dh^T  (5 k-steps), wave ni = wv
  {
    __builtin_amdgcn_s_setprio(1);
    f32x4 acc = (f32x4){0.f, 0.f, 0.f, 0.f};
    #pragma unroll
    for (int ks = 0; ks < 5; ks++) {
      bf16x8 a = *(const bf16x8*)&T3u[l15 * 168 + ks * 32 + cp * 8];
      bf16x8 bfr = *(const bf16x8*)&mdh[(wv * 16 + l15) * 160 + ks * 32 + cp * 8];
      acc = __builtin_amdgcn_mfma_f32_16x16x32_bf16(a, bfr, acc, 0, 0, 0);
    }
    __builtin_amdgcn_s_setprio(0);
    float* op = out + (((size_t)b * 512 + o) * 64 + out_r0) * 64;
    #pragma unroll
    for (int j = 0; j < 4; j++)
      op[(rb + j) * 64 + wv * 16 + l15] = acc[j];
  }
}

extern "C" void kernel_launch(void* const* d_in, const int* in_sizes, int n_in,
                              void* d_out, int out_size, void* d_ws, size_t ws_size,
                              hipStream_t stream) {
  const float* x     = (const float*)d_in[0];
  const float* w     = (const float*)d_in[1];
  const float* aw    = (const float*)d_in[2];
  const float* ab    = (const float*)d_in[3];
  const float* swgt  = (const float*)d_in[4];
  const float* bias  = (const float*)d_in[5];
  const float* sw0   = (const float*)d_in[6];
  const float* sb0   = (const float*)d_in[7];
  const float* sw1   = (const float*)d_in[8];
  const float* sb1   = (const float*)d_in[9];
  const float* sw2   = (const float*)d_in[10];
  const float* sb2   = (const float*)d_in[11];
  const float* sw3   = (const float*)d_in[12];
  const float* sb3   = (const float*)d_in[13];
  const float* kscl  = (const float*)d_in[14];
  const float* ema   = (const float*)d_in[15];

  float* ws  = (float*)d_ws;
  char*  wsb = (char*)d_ws;
  u16* wbp = (u16*)(wsb + OFFB_WB);
  u16* y2  = (u16*)(wsb + OFFB_Y2);
  u16* y1  = (u16*)(wsb + OFFB_Y1);
  u16* muv = (u16*)(wsb + OFFB_MUV);
  u16* muh = (u16*)(wsb + OFFB_MUH);
  u16* mdv = (u16*)(wsb + OFFB_MDV);
  u16* mdh = (u16*)(wsb + OFFB_MDH);

  k_setup<<<dim3(1), dim3(256), 0, stream>>>(sw0, sb0, sw1, sb1, sw2, sb2, ws);
  k_stkw<<<dim3(72), dim3(256), 0, stream>>>(w, aw, ab, sw3, sb3, kscl, ema, ws);
  k_wb<<<dim3(128, 8), dim3(256), 0, stream>>>(swgt, ws, wbp);
  k_tdw<<<dim3(67, 8, 8), dim3(256), 0, stream>>>(x, ws, y1);
  k_gemm<<<dim3(35, 4, 8), dim3(256), 0, stream>>>(wbp, y1, bias, y2);
  k_updown<<<dim3(4, 512, 8), dim3(256), 0, stream>>>(y2, muv, muh, mdv, mdh, (float*)d_out);
}